// Round 2
// baseline (340.454 us; speedup 1.0000x reference)
//
#include <hip/hip_runtime.h>

typedef __bf16 bf16_t;
typedef __bf16 bf16x8 __attribute__((ext_vector_type(8)));
typedef __bf16 bf16x4 __attribute__((ext_vector_type(4)));
typedef float  f32x4  __attribute__((ext_vector_type(4)));

#define MFMA16(a,b,c) __builtin_amdgcn_mfma_f32_16x16x32_bf16((a),(b),(c),0,0,0)

#define NB 4          // batch
#define LL 4096       // seq
#define CC 1024       // channels
#define HH 8          // heads
#define RR 512        // low-rank seq

// ---------------- K0: convert 4 weight matrices (1024x1024 f32) -> bf16 ----------------
__global__ void k_wcvt(const float* __restrict__ w0, const float* __restrict__ w1,
                       const float* __restrict__ w2, const float* __restrict__ w3,
                       bf16_t* __restrict__ dst) {
  const float* src = (blockIdx.y == 0) ? w0 : (blockIdx.y == 1) ? w1 : (blockIdx.y == 2) ? w2 : w3;
  int idx = blockIdx.x * 256 + threadIdx.x;       // one thread = 4 elems
  f32x4 v = *(const f32x4*)&src[(size_t)idx * 4];
  bf16x4 o;
#pragma unroll
  for (int j = 0; j < 4; ++j) o[j] = (bf16_t)v[j];
  *(bf16x4*)&dst[(size_t)blockIdx.y * 1048576 + (size_t)idx * 4] = o;
}

// ---------------- K1: downsample x (B,4096,1024) f32 -> xd (B,512,1024) bf16 ----------------
// coords = 8i+3.5 exactly -> xd[i] = 0.5*(x[8i+3]+x[8i+4])
__global__ void k_down(const float* __restrict__ x, bf16_t* __restrict__ xd) {
  int idx = blockIdx.x * 256 + threadIdx.x;       // one thread = 4 elems
  int c4  = idx & 255;
  int row = idx >> 8;                              // b*512 + i
  int b = row >> 9, i = row & 511;
  const float* p0 = x + (size_t)(b * LL + 8 * i + 3) * CC + c4 * 4;
  f32x4 a = *(const f32x4*)p0;
  f32x4 bb = *(const f32x4*)(p0 + CC);
  bf16x4 o;
#pragma unroll
  for (int j = 0; j < 4; ++j) o[j] = (bf16_t)(0.5f * (a[j] + bb[j]));
  *(bf16x4*)&xd[(size_t)row * CC + c4 * 4] = o;
}

// ---------------- GEMM: C[M,N] = A[M,K=1024] * W[N,K=1024]^T, 128x128 tile ----------------
// EPI 0: bf16 row-major out (q/k; blockIdx.z selects Wq/Wk and out buffer)
// EPI 1: bf16 transposed out -> Vt (B,H,128,512)
// EPI 2: silu -> f32 row-major out (lowrank output)
__device__ __forceinline__ void stage_tile(const bf16_t* __restrict__ g, bf16_t* __restrict__ s, int t) {
#pragma unroll
  for (int j = 0; j < 2; ++j) {
    int c = t + j * 256;          // 0..511 chunks of 16B
    int r = c >> 2, q = c & 3;    // row 0..127, quarter
    *(bf16x8*)&s[r * 40 + q * 8] = *(const bf16x8*)&g[r * 1024 + q * 8];
  }
}

template <int EPI>
__global__ __launch_bounds__(256) void k_gemm(const bf16_t* __restrict__ A,
                                              const bf16_t* __restrict__ Wa,
                                              const bf16_t* __restrict__ Wb,
                                              bf16_t* __restrict__ outB_a,
                                              bf16_t* __restrict__ outB_b,
                                              float* __restrict__ outF) {
  __shared__ bf16_t sA[128 * 40];   // rows padded 32->40 (conflict-free ds_read_b128)
  __shared__ bf16_t sB[128 * 40];
  const bf16_t* W = (blockIdx.z == 0) ? Wa : Wb;
  bf16_t* outB = (blockIdx.z == 0) ? outB_a : outB_b;
  int t = threadIdx.x;
  int lane = t & 63, w = t >> 6;
  int wr = w >> 1, wc = w & 1;
  int lr = lane & 15, quad = lane >> 4;
  int m0 = blockIdx.y * 128, n0 = blockIdx.x * 128;
  f32x4 acc[4][4] = {};
  for (int k0 = 0; k0 < 1024; k0 += 32) {
    __syncthreads();
    stage_tile(A + (size_t)m0 * 1024 + k0, sA, t);
    stage_tile(W + (size_t)n0 * 1024 + k0, sB, t);
    __syncthreads();
    bf16x8 af[4], bfr[4];
#pragma unroll
    for (int i = 0; i < 4; ++i) af[i]  = *(bf16x8*)&sA[(wr * 64 + i * 16 + lr) * 40 + quad * 8];
#pragma unroll
    for (int i = 0; i < 4; ++i) bfr[i] = *(bf16x8*)&sB[(wc * 64 + i * 16 + lr) * 40 + quad * 8];
#pragma unroll
    for (int i = 0; i < 4; ++i)
#pragma unroll
      for (int j = 0; j < 4; ++j)
        acc[i][j] = MFMA16(af[i], bfr[j], acc[i][j]);
  }
#pragma unroll
  for (int i = 0; i < 4; ++i) {
#pragma unroll
    for (int j = 0; j < 4; ++j) {
      int row0 = m0 + wr * 64 + i * 16 + quad * 4;   // +reg
      int col  = n0 + wc * 64 + j * 16 + lr;
      if (EPI == 0) {
#pragma unroll
        for (int rg = 0; rg < 4; ++rg) outB[(size_t)(row0 + rg) * 1024 + col] = (bf16_t)acc[i][j][rg];
      } else if (EPI == 1) {
        int b = row0 >> 9, ii = row0 & 511;          // row0 = b*512 + i (seq)
        int h = col >> 7, nn = col & 127;
        bf16x4 pk;
#pragma unroll
        for (int rg = 0; rg < 4; ++rg) pk[rg] = (bf16_t)acc[i][j][rg];
        *(bf16x4*)&outB[(size_t)((b * HH + h) * 128 + nn) * 512 + ii] = pk;
      } else {
#pragma unroll
        for (int rg = 0; rg < 4; ++rg) {
          float v = acc[i][j][rg];
          float s = v / (1.f + __expf(-v));
          outF[(size_t)(row0 + rg) * 1024 + col] = s;
        }
      }
    }
  }
}

// ---------------- K3: rmsnorm(d=64) + rope (pos = head index!) ----------------
// src q/k bf16 (B,512,H,2,64); dst q1,q2,k1,k2 bf16 (B,H,512,64)
__global__ __launch_bounds__(256) void k_normrope(const bf16_t* __restrict__ qb,
                                                  const bf16_t* __restrict__ kb,
                                                  const float* __restrict__ qw,
                                                  const float* __restrict__ kw,
                                                  bf16_t* __restrict__ q1, bf16_t* __restrict__ q2,
                                                  bf16_t* __restrict__ k1, bf16_t* __restrict__ k2) {
  int wid = blockIdx.x * 4 + (threadIdx.x >> 6);
  int lane = threadIdx.x & 63;
  int z = wid >> 15;          // 0=q 1=k
  int rid = wid & 32767;      // ((b*512+i)*8+h)*2+slot
  int slot = rid & 1, h = (rid >> 1) & 7, i = (rid >> 4) & 511, b = rid >> 13;
  float v = (float)((z ? kb : qb)[(size_t)rid * 64 + lane]);
  float ss = v * v;
#pragma unroll
  for (int m = 1; m <= 32; m <<= 1) ss += __shfl_xor(ss, m);
  float rms = sqrtf(ss * (1.f / 64.f) + 1e-6f);
  float nw = (z ? kw : qw)[lane];
  float n = v / rms * nw;
  int j = lane & 31;
  float freq = exp2f((float)j * (-13.287712379549449f / 32.f));  // 10000^(-j/32)
  float ang = (float)h * freq;
  float sn, cs;
  __sincosf(ang, &sn, &cs);
  float p = __shfl_xor(n, 32);
  float outv = (lane < 32) ? (n * cs - p * sn) : (p * sn + n * cs);
  bf16_t* dst = z ? (slot ? k2 : k1) : (slot ? q2 : q1);
  dst[(size_t)((b * HH + h) * RR + i) * 64 + lane] = (bf16_t)outv;
}

// ---------------- K4: fused differential attention + head rmsnorm ----------------
// block = 1 wave; handles 16 q rows of one (b,h). Full 512-wide score rows in LDS.
__global__ __launch_bounds__(64) void k_attn(const bf16_t* __restrict__ q1, const bf16_t* __restrict__ q2,
                                             const bf16_t* __restrict__ k1, const bf16_t* __restrict__ k2,
                                             const bf16_t* __restrict__ vt,
                                             const float* __restrict__ lq1, const float* __restrict__ lk1,
                                             const float* __restrict__ lq2, const float* __restrict__ lk2,
                                             const float* __restrict__ hw, bf16_t* __restrict__ anorm) {
  __shared__ float  S[16 * 516];   // stride 516: conflict-light softmax
  __shared__ bf16_t P[16 * 520];   // stride 520: 16B-aligned rows for ds_read_b128
  int lane = threadIdx.x;
  int lr = lane & 15, quad = lane >> 4;
  int qt = blockIdx.x, bh = blockIdx.y;
  int b = bh >> 3, h = bh & 7;

  // lambda scalar (64-wide dot products, butterfly reduce)
  float t1 = lq1[lane] * lk1[lane];
  float t2 = lq2[lane] * lk2[lane];
#pragma unroll
  for (int m = 1; m <= 32; m <<= 1) { t1 += __shfl_xor(t1, m); t2 += __shfl_xor(t2, m); }
  float lam = expf(t1) - expf(t2) + 0.8f;

  const bf16_t* q1b = q1 + (size_t)(bh * RR + qt * 16) * 64;
  const bf16_t* q2b = q2 + (size_t)(bh * RR + qt * 16) * 64;
  const bf16_t* k1b = k1 + (size_t)bh * RR * 64;
  const bf16_t* k2b = k2 + (size_t)bh * RR * 64;
  const bf16_t* vtb = vt + (size_t)bh * 128 * 512;

  bf16x8 a1[2], a2[2];
#pragma unroll
  for (int kk = 0; kk < 2; ++kk) {
    a1[kk] = *(const bf16x8*)&q1b[lr * 64 + kk * 32 + quad * 8];
    a2[kk] = *(const bf16x8*)&q2b[lr * 64 + kk * 32 + quad * 8];
  }

  // ---- scores 1 ----
  for (int kt = 0; kt < 32; ++kt) {
    f32x4 acc = {};
    const bf16_t* kr = k1b + (kt * 16 + lr) * 64 + quad * 8;
    acc = MFMA16(a1[0], *(const bf16x8*)kr, acc);
    acc = MFMA16(a1[1], *(const bf16x8*)(kr + 32), acc);
#pragma unroll
    for (int rg = 0; rg < 4; ++rg) S[(quad * 4 + rg) * 516 + kt * 16 + lr] = acc[rg] * 0.125f;
  }
  __syncthreads();
  // ---- softmax1 -> P (bf16) ----
  {
    int r = lane & 15, sub = lane >> 4;
    float mx = -3.0e38f;
    for (int c = sub; c < 512; c += 4) mx = fmaxf(mx, S[r * 516 + c]);
    mx = fmaxf(mx, __shfl_xor(mx, 16)); mx = fmaxf(mx, __shfl_xor(mx, 32));
    float sum = 0.f;
    for (int c = sub; c < 512; c += 4) { float e = __expf(S[r * 516 + c] - mx); S[r * 516 + c] = e; sum += e; }
    sum += __shfl_xor(sum, 16); sum += __shfl_xor(sum, 32);
    float inv = 1.f / sum;
    for (int c = sub; c < 512; c += 4) P[r * 520 + c] = (bf16_t)(S[r * 516 + c] * inv);
  }
  __syncthreads();
  // ---- scores 2 ----
  for (int kt = 0; kt < 32; ++kt) {
    f32x4 acc = {};
    const bf16_t* kr = k2b + (kt * 16 + lr) * 64 + quad * 8;
    acc = MFMA16(a2[0], *(const bf16x8*)kr, acc);
    acc = MFMA16(a2[1], *(const bf16x8*)(kr + 32), acc);
#pragma unroll
    for (int rg = 0; rg < 4; ++rg) S[(quad * 4 + rg) * 516 + kt * 16 + lr] = acc[rg] * 0.125f;
  }
  __syncthreads();
  // ---- softmax2 + combine: P = P1 - lam*P2 ----
  {
    int r = lane & 15, sub = lane >> 4;
    float mx = -3.0e38f;
    for (int c = sub; c < 512; c += 4) mx = fmaxf(mx, S[r * 516 + c]);
    mx = fmaxf(mx, __shfl_xor(mx, 16)); mx = fmaxf(mx, __shfl_xor(mx, 32));
    float sum = 0.f;
    for (int c = sub; c < 512; c += 4) { float e = __expf(S[r * 516 + c] - mx); S[r * 516 + c] = e; sum += e; }
    sum += __shfl_xor(sum, 16); sum += __shfl_xor(sum, 32);
    float inv = 1.f / sum;
    for (int c = sub; c < 512; c += 4) {
      float val = (float)P[r * 520 + c] - lam * (S[r * 516 + c] * inv);
      P[r * 520 + c] = (bf16_t)val;
    }
  }
  __syncthreads();
  // ---- PV: O[16,128] = P[16,512] @ V[512,128] (via Vt) ----
  f32x4 accO[8] = {};
  for (int ks = 0; ks < 16; ++ks) {
    bf16x8 pf = *(bf16x8*)&P[lr * 520 + ks * 32 + quad * 8];
#pragma unroll
    for (int nt = 0; nt < 8; ++nt) {
      bf16x8 vf = *(const bf16x8*)&vtb[(nt * 16 + lr) * 512 + ks * 32 + quad * 8];
      accO[nt] = MFMA16(pf, vf, accO[nt]);
    }
  }
  // ---- head rmsnorm (over 128) * head_norm_w * 0.2 -> anorm (2048,1024) bf16 ----
  float ssr[4] = {0.f, 0.f, 0.f, 0.f};
#pragma unroll
  for (int nt = 0; nt < 8; ++nt)
#pragma unroll
    for (int rg = 0; rg < 4; ++rg) ssr[rg] += accO[nt][rg] * accO[nt][rg];
#pragma unroll
  for (int m = 1; m <= 8; m <<= 1)
#pragma unroll
    for (int rg = 0; rg < 4; ++rg) ssr[rg] += __shfl_xor(ssr[rg], m);
  float rinv[4];
#pragma unroll
  for (int rg = 0; rg < 4; ++rg) rinv[rg] = 0.2f / sqrtf(ssr[rg] * (1.f / 128.f) + 1e-6f);
#pragma unroll
  for (int nt = 0; nt < 8; ++nt) {
    float wcol = hw[nt * 16 + lr];
#pragma unroll
    for (int rg = 0; rg < 4; ++rg) {
      int i = qt * 16 + quad * 4 + rg;
      anorm[(size_t)(b * RR + i) * 1024 + h * 128 + nt * 16 + lr] = (bf16_t)(accO[nt][rg] * rinv[rg] * wcol);
    }
  }
}

// ---------------- K6: upsample lowrank (B,512,1024) f32 -> full (B,4096,1024) f32 ----------------
__global__ void k_up(const float* __restrict__ lrk, float* __restrict__ out) {
  int j = blockIdx.x;
  int b = blockIdx.y;
  int c = threadIdx.x * 4;
  float coord = 0.125f * (float)j - 0.4375f;
  coord = fminf(fmaxf(coord, 0.f), 511.f);
  int lo = (int)floorf(coord);
  int hi = lo + 1 < 511 ? lo + 1 : 511;
  float w = coord - (float)lo;
  f32x4 a = *(const f32x4*)&lrk[(size_t)(b * RR + lo) * CC + c];
  f32x4 bb = *(const f32x4*)&lrk[(size_t)(b * RR + hi) * CC + c];
  f32x4 o;
#pragma unroll
  for (int t = 0; t < 4; ++t) o[t] = a[t] * (1.f - w) + bb[t] * w;
  *(f32x4*)&out[(size_t)(b * LL + j) * CC + c] = o;
}

extern "C" void kernel_launch(void* const* d_in, const int* in_sizes, int n_in,
                              void* d_out, int out_size, void* d_ws, size_t ws_size,
                              hipStream_t stream) {
  (void)in_sizes; (void)n_in; (void)out_size; (void)ws_size;
  const float* x   = (const float*)d_in[0];
  const float* Wq  = (const float*)d_in[1];
  const float* Wk  = (const float*)d_in[2];
  const float* Wv  = (const float*)d_in[3];
  const float* Wo  = (const float*)d_in[4];
  const float* qw  = (const float*)d_in[5];
  const float* kw  = (const float*)d_in[6];
  const float* hw  = (const float*)d_in[7];
  const float* lq1 = (const float*)d_in[8];
  const float* lk1 = (const float*)d_in[9];
  const float* lq2 = (const float*)d_in[10];
  const float* lk2 = (const float*)d_in[11];
  float* out = (float*)d_out;

  char* ws = (char*)d_ws;
  bf16_t* wbf   = (bf16_t*)(ws);                    // 8 MB: Wq,Wk,Wv,Wo bf16 (2MB each)
  bf16_t* xd    = (bf16_t*)(ws + (8u << 20));       // 4 MB
  bf16_t* qbuf  = (bf16_t*)(ws + (12u << 20));      // 4 MB (B,512,1024) bf16
  bf16_t* kbuf  = (bf16_t*)(ws + (16u << 20));      // 4 MB
  bf16_t* vt    = (bf16_t*)(ws + (20u << 20));      // 4 MB (B,H,128,512)
  bf16_t* q1    = (bf16_t*)(ws + (24u << 20));      // 2 MB each
  bf16_t* q2    = (bf16_t*)(ws + (26u << 20));
  bf16_t* k1    = (bf16_t*)(ws + (28u << 20));
  bf16_t* k2    = (bf16_t*)(ws + (30u << 20));
  bf16_t* anorm = (bf16_t*)(ws + (12u << 20));      // aliases qbuf (dead after normrope)

  bf16_t* wq_b = wbf;
  bf16_t* wk_b = wbf + (1u << 20);
  bf16_t* wv_b = wbf + (2u << 20);
  bf16_t* wo_b = wbf + (3u << 20);

  float* lowrank = out + (size_t)NB * LL * CC;      // second output region (f32)

  k_wcvt<<<dim3(1024, 4), 256, 0, stream>>>(Wq, Wk, Wv, Wo, wbf);
  k_down<<<2048, 256, 0, stream>>>(x, xd);
  k_gemm<0><<<dim3(8, 16, 2), 256, 0, stream>>>(xd, wq_b, wk_b, qbuf, kbuf, nullptr);
  k_gemm<1><<<dim3(8, 16, 1), 256, 0, stream>>>(xd, wv_b, wv_b, vt, nullptr, nullptr);
  k_normrope<<<16384, 256, 0, stream>>>(qbuf, kbuf, qw, kw, q1, q2, k1, k2);
  k_attn<<<dim3(32, 32), 64, 0, stream>>>(q1, q2, k1, k2, vt, lq1, lk1, lq2, lk2, hw, anorm);
  k_gemm<2><<<dim3(8, 16, 1), 256, 0, stream>>>(anorm, wo_b, wo_b, nullptr, nullptr, lowrank);
  k_up<<<dim3(4096, 4), 256, 0, stream>>>(lowrank, out);
}

// Round 3
// 288.154 us; speedup vs baseline: 1.1815x; 1.1815x over previous
//
#include <hip/hip_runtime.h>

typedef __bf16 bf16_t;
typedef __bf16 bf16x8 __attribute__((ext_vector_type(8)));
typedef __bf16 bf16x4 __attribute__((ext_vector_type(4)));
typedef __bf16 bf16x2 __attribute__((ext_vector_type(2)));
typedef float  f32x4  __attribute__((ext_vector_type(4)));

#define MFMA16(a,b,c) __builtin_amdgcn_mfma_f32_16x16x32_bf16((a),(b),(c),0,0,0)

#define NB 4          // batch
#define LL 4096       // seq
#define CC 1024       // channels
#define HH 8          // heads
#define RR 512        // low-rank seq

// ---------------- K0: convert 4 weight matrices (1024x1024 f32) -> bf16 ----------------
__global__ void k_wcvt(const float* __restrict__ w0, const float* __restrict__ w1,
                       const float* __restrict__ w2, const float* __restrict__ w3,
                       bf16_t* __restrict__ dst) {
  const float* src = (blockIdx.y == 0) ? w0 : (blockIdx.y == 1) ? w1 : (blockIdx.y == 2) ? w2 : w3;
  int idx = blockIdx.x * 256 + threadIdx.x;       // one thread = 4 elems
  f32x4 v = *(const f32x4*)&src[(size_t)idx * 4];
  bf16x4 o;
#pragma unroll
  for (int j = 0; j < 4; ++j) o[j] = (bf16_t)v[j];
  *(bf16x4*)&dst[(size_t)blockIdx.y * 1048576 + (size_t)idx * 4] = o;
}

// ---------------- K1: downsample x (B,4096,1024) f32 -> xd (B,512,1024) bf16 ----------------
// coords = 8i+3.5 exactly -> xd[i] = 0.5*(x[8i+3]+x[8i+4])
__global__ void k_down(const float* __restrict__ x, bf16_t* __restrict__ xd) {
  int idx = blockIdx.x * 256 + threadIdx.x;       // one thread = 4 elems
  int c4  = idx & 255;
  int row = idx >> 8;                              // b*512 + i
  int b = row >> 9, i = row & 511;
  const float* p0 = x + (size_t)(b * LL + 8 * i + 3) * CC + c4 * 4;
  f32x4 a = *(const f32x4*)p0;
  f32x4 bb = *(const f32x4*)(p0 + CC);
  bf16x4 o;
#pragma unroll
  for (int j = 0; j < 4; ++j) o[j] = (bf16_t)(0.5f * (a[j] + bb[j]));
  *(bf16x4*)&xd[(size_t)row * CC + c4 * 4] = o;
}

// ---------------- async 16B global->LDS staging (m97 pattern: unpadded stride-32 rows) ----
template <int CH>
__device__ __forceinline__ void stage_async(const bf16_t* __restrict__ g, bf16_t* __restrict__ s, int t) {
#pragma unroll
  for (int j = 0; j < CH; ++j) {
    int c = t + j * 256;                     // 16B chunk id; lane-contiguous per wave
    const bf16_t* ga = g + (c >> 2) * 1024 + (c & 3) * 8;
    bf16_t* la = s + c * 8;
    __builtin_amdgcn_global_load_lds((const __attribute__((address_space(1))) void*)ga,
                                     (__attribute__((address_space(3))) void*)la, 16, 0, 0);
  }
}

// ---------------- GEMM core: C[M,N] = A[M,1024] * W[N,1024]^T ----------------
// MODE 0 (BM=128): QKV fused. z=0 -> rmsnorm+rope -> q1/q2 (scaled 0.125)
//                              z=1 -> rmsnorm+rope -> k1/k2
//                              z=2 -> Vt transposed bf16 (B,H,128,512)
// MODE 1 (BM=64):  Wo + silu -> f32 lowrank
template <int MODE, int BM>
__global__ __launch_bounds__(256) void k_gemm(const bf16_t* __restrict__ A,
                                              const bf16_t* __restrict__ wbf,
                                              const float* __restrict__ qw,
                                              const float* __restrict__ kw,
                                              bf16_t* __restrict__ q1, bf16_t* __restrict__ q2,
                                              bf16_t* __restrict__ k1, bf16_t* __restrict__ k2,
                                              bf16_t* __restrict__ vt, float* __restrict__ outF) {
  __shared__ bf16_t sA[BM * 32];
  __shared__ bf16_t sB[128 * 32];
  const int z = (MODE == 0) ? blockIdx.z : 3;
  const bf16_t* W = wbf + (size_t)z * (1u << 20);
  int t = threadIdx.x;
  int lane = t & 63, w = t >> 6;
  int wr = w >> 1, wc = w & 1;
  int lr = lane & 15, quad = lane >> 4;
  int m0 = blockIdx.y * BM, n0 = blockIdx.x * 128;
  const int NI = BM / 32;                     // 16-row tiles per wave
  f32x4 acc[NI][4] = {};
  for (int k0 = 0; k0 < 1024; k0 += 32) {
    __syncthreads();
    stage_async<BM / 64>(A + (size_t)m0 * 1024 + k0, sA, t);
    stage_async<2>(W + (size_t)n0 * 1024 + k0, sB, t);
    __syncthreads();                          // compiler emits vmcnt(0) drain here
    bf16x8 af[NI], bfr[4];
#pragma unroll
    for (int i = 0; i < NI; ++i) af[i] = *(bf16x8*)&sA[(wr * (BM / 2) + i * 16 + lr) * 32 + quad * 8];
#pragma unroll
    for (int j = 0; j < 4; ++j) bfr[j] = *(bf16x8*)&sB[(wc * 64 + j * 16 + lr) * 32 + quad * 8];
#pragma unroll
    for (int i = 0; i < NI; ++i)
#pragma unroll
      for (int j = 0; j < 4; ++j)
        acc[i][j] = MFMA16(af[i], bfr[j], acc[i][j]);
  }

  if (MODE == 1) {
    // silu -> f32
#pragma unroll
    for (int i = 0; i < NI; ++i)
#pragma unroll
      for (int j = 0; j < 4; ++j) {
        int row0 = m0 + wr * (BM / 2) + i * 16 + quad * 4;
        int col  = n0 + wc * 64 + j * 16 + lr;
#pragma unroll
        for (int rg = 0; rg < 4; ++rg) {
          float v = acc[i][j][rg];
          outF[(size_t)(row0 + rg) * 1024 + col] = v / (1.f + __expf(-v));
        }
      }
    return;
  }

  if (z == 2) {
    // Vt transposed bf16 out
#pragma unroll
    for (int i = 0; i < NI; ++i)
#pragma unroll
      for (int j = 0; j < 4; ++j) {
        int row0 = m0 + wr * (BM / 2) + i * 16 + quad * 4;
        int col  = n0 + wc * 64 + j * 16 + lr;
        int b = row0 >> 9, ii = row0 & 511;
        int h = col >> 7, nn = col & 127;
        bf16x4 pk;
#pragma unroll
        for (int rg = 0; rg < 4; ++rg) pk[rg] = (bf16_t)acc[i][j][rg];
        *(bf16x4*)&vt[(size_t)((b * HH + h) * 128 + nn) * 512 + ii] = pk;
      }
    return;
  }

  // z<2: fused rmsnorm(64) + rope (pos = head idx) epilogue.
  // wave col span = n0+wc*64 .. +63 = exactly one (h,slot,d0..63) group.
  {
    const float* nw = z ? kw : qw;
    int colbase = n0 + wc * 64;
    int h = colbase >> 7;
    int slot = (colbase >> 6) & 1;
    bf16_t* dst = (z == 0) ? (slot ? q2 : q1) : (slot ? k2 : k1);
    float qs = (z == 0) ? 0.125f : 1.0f;      // fold attn scale into q
    float w0 = nw[lr], w1 = nw[16 + lr], w2 = nw[32 + lr], w3 = nw[48 + lr];
    const float nlog = -13.287712379549449f / 32.f;   // -log2(10000)/32
    float f0 = exp2f((float)lr * nlog);
    float f1 = exp2f((float)(16 + lr) * nlog);
    float sn0, cs0, sn1, cs1;
    __sincosf((float)h * f0, &sn0, &cs0);
    __sincosf((float)h * f1, &sn1, &cs1);
#pragma unroll
    for (int i = 0; i < NI; ++i) {
#pragma unroll
      for (int rg = 0; rg < 4; ++rg) {
        float v0 = acc[i][0][rg], v1 = acc[i][1][rg], v2 = acc[i][2][rg], v3 = acc[i][3][rg];
        float ss = v0 * v0 + v1 * v1 + v2 * v2 + v3 * v3;
#pragma unroll
        for (int m = 1; m <= 8; m <<= 1) ss += __shfl_xor(ss, m);   // over 16 lr lanes (same row)
        float rinv = qs / sqrtf(ss * (1.f / 64.f) + 1e-6f);
        float n0v = v0 * rinv * w0, n1v = v1 * rinv * w1, n2v = v2 * rinv * w2, n3v = v3 * rinv * w3;
        float o0 = n0v * cs0 - n2v * sn0;
        float o1 = n1v * cs1 - n3v * sn1;
        float o2 = n0v * sn0 + n2v * cs0;
        float o3 = n1v * sn1 + n3v * cs1;
        int row = m0 + wr * (BM / 2) + i * 16 + quad * 4 + rg;
        int b = row >> 9, seq = row & 511;
        size_t base = ((size_t)((b * HH + h) * RR + seq)) * 64;
        dst[base + lr]      = (bf16_t)o0;
        dst[base + 16 + lr] = (bf16_t)o1;
        dst[base + 32 + lr] = (bf16_t)o2;
        dst[base + 48 + lr] = (bf16_t)o3;
      }
    }
  }
}

// ---------------- K4: fused differential attention, register softmax ----------------
// 1 wave / block; 16 q rows of one (b,h); scores live in VGPRs, P round-trips LDS once.
__global__ __launch_bounds__(64, 2) void k_attn(const bf16_t* __restrict__ q1, const bf16_t* __restrict__ q2,
                                                const bf16_t* __restrict__ k1, const bf16_t* __restrict__ k2,
                                                const bf16_t* __restrict__ vt,
                                                const float* __restrict__ lq1, const float* __restrict__ lk1,
                                                const float* __restrict__ lq2, const float* __restrict__ lk2,
                                                const float* __restrict__ hw, bf16_t* __restrict__ anorm) {
  __shared__ bf16_t P[16 * 520];   // combined P1 - lam*P2, A-layout source for PV
  int lane = threadIdx.x;
  int lr = lane & 15, quad = lane >> 4;
  int qt = blockIdx.x, bh = blockIdx.y;
  int b = bh >> 3, h = bh & 7;

  float t1 = lq1[lane] * lk1[lane];
  float t2 = lq2[lane] * lk2[lane];
#pragma unroll
  for (int m = 1; m <= 32; m <<= 1) { t1 += __shfl_xor(t1, m); t2 += __shfl_xor(t2, m); }
  float lam = expf(t1) - expf(t2) + 0.8f;

  const bf16_t* q1b = q1 + (size_t)(bh * RR + qt * 16) * 64;
  const bf16_t* q2b = q2 + (size_t)(bh * RR + qt * 16) * 64;
  const bf16_t* k1b = k1 + (size_t)bh * RR * 64;
  const bf16_t* k2b = k2 + (size_t)bh * RR * 64;
  const bf16_t* vtb = vt + (size_t)bh * 128 * 512;

  bf16x8 a1[2], a2[2];
#pragma unroll
  for (int kk = 0; kk < 2; ++kk) {
    a1[kk] = *(const bf16x8*)&q1b[lr * 64 + kk * 32 + quad * 8];
    a2[kk] = *(const bf16x8*)&q2b[lr * 64 + kk * 32 + quad * 8];
  }

  f32x4 sc[32];
  // ---- scores 1 (q pre-scaled by 0.125) ----
#pragma unroll
  for (int kt = 0; kt < 32; ++kt) {
    const bf16_t* kr = k1b + (kt * 16 + lr) * 64 + quad * 8;
    f32x4 a = {};
    a = MFMA16(a1[0], *(const bf16x8*)kr, a);
    a = MFMA16(a1[1], *(const bf16x8*)(kr + 32), a);
    sc[kt] = a;
  }
  // ---- softmax1 in registers: row r = quad*4+rg lives in 16 lr-lanes x 32 kt ----
  float mx[4] = {-3e38f, -3e38f, -3e38f, -3e38f};
#pragma unroll
  for (int kt = 0; kt < 32; ++kt)
#pragma unroll
    for (int rg = 0; rg < 4; ++rg) mx[rg] = fmaxf(mx[rg], sc[kt][rg]);
#pragma unroll
  for (int m = 1; m <= 8; m <<= 1)
#pragma unroll
    for (int rg = 0; rg < 4; ++rg) mx[rg] = fmaxf(mx[rg], __shfl_xor(mx[rg], m));
  float sm[4] = {};
#pragma unroll
  for (int kt = 0; kt < 32; ++kt)
#pragma unroll
    for (int rg = 0; rg < 4; ++rg) { float e = __expf(sc[kt][rg] - mx[rg]); sc[kt][rg] = e; sm[rg] += e; }
#pragma unroll
  for (int m = 1; m <= 8; m <<= 1)
#pragma unroll
    for (int rg = 0; rg < 4; ++rg) sm[rg] += __shfl_xor(sm[rg], m);
  float inv[4];
#pragma unroll
  for (int rg = 0; rg < 4; ++rg) inv[rg] = 1.f / sm[rg];
  bf16x2 p1[32][2];                      // normalized P1 packed in regs
#pragma unroll
  for (int kt = 0; kt < 32; ++kt) {
    p1[kt][0][0] = (bf16_t)(sc[kt][0] * inv[0]);
    p1[kt][0][1] = (bf16_t)(sc[kt][1] * inv[1]);
    p1[kt][1][0] = (bf16_t)(sc[kt][2] * inv[2]);
    p1[kt][1][1] = (bf16_t)(sc[kt][3] * inv[3]);
  }
  // ---- scores 2 (reuse sc regs) ----
#pragma unroll
  for (int kt = 0; kt < 32; ++kt) {
    const bf16_t* kr = k2b + (kt * 16 + lr) * 64 + quad * 8;
    f32x4 a = {};
    a = MFMA16(a2[0], *(const bf16x8*)kr, a);
    a = MFMA16(a2[1], *(const bf16x8*)(kr + 32), a);
    sc[kt] = a;
  }
  float mx2[4] = {-3e38f, -3e38f, -3e38f, -3e38f};
#pragma unroll
  for (int kt = 0; kt < 32; ++kt)
#pragma unroll
    for (int rg = 0; rg < 4; ++rg) mx2[rg] = fmaxf(mx2[rg], sc[kt][rg]);
#pragma unroll
  for (int m = 1; m <= 8; m <<= 1)
#pragma unroll
    for (int rg = 0; rg < 4; ++rg) mx2[rg] = fmaxf(mx2[rg], __shfl_xor(mx2[rg], m));
  float sm2[4] = {};
#pragma unroll
  for (int kt = 0; kt < 32; ++kt)
#pragma unroll
    for (int rg = 0; rg < 4; ++rg) { float e = __expf(sc[kt][rg] - mx2[rg]); sc[kt][rg] = e; sm2[rg] += e; }
#pragma unroll
  for (int m = 1; m <= 8; m <<= 1)
#pragma unroll
    for (int rg = 0; rg < 4; ++rg) sm2[rg] += __shfl_xor(sm2[rg], m);
  float inv2[4];
#pragma unroll
  for (int rg = 0; rg < 4; ++rg) inv2[rg] = lam / sm2[rg];
  // ---- combine and store P = P1 - lam*P2 (single LDS write pass) ----
#pragma unroll
  for (int kt = 0; kt < 32; ++kt)
#pragma unroll
    for (int rg = 0; rg < 4; ++rg) {
      float v = (float)p1[kt][rg >> 1][rg & 1] - sc[kt][rg] * inv2[rg];
      P[(quad * 4 + rg) * 520 + kt * 16 + lr] = (bf16_t)v;
    }
  __syncthreads();   // single-wave: cheap; orders LDS write->read
  // ---- PV: O[16,128] = P[16,512] @ V[512,128] ----
  f32x4 accO[8] = {};
#pragma unroll
  for (int ks = 0; ks < 16; ++ks) {
    bf16x8 pf = *(bf16x8*)&P[lr * 520 + ks * 32 + quad * 8];
#pragma unroll
    for (int nt = 0; nt < 8; ++nt) {
      bf16x8 vf = *(const bf16x8*)&vtb[(nt * 16 + lr) * 512 + ks * 32 + quad * 8];
      accO[nt] = MFMA16(pf, vf, accO[nt]);
    }
  }
  // ---- head rmsnorm(128) * hw * 0.2 -> anorm (B*512, 1024) bf16 ----
  float ssr[4] = {};
#pragma unroll
  for (int nt = 0; nt < 8; ++nt)
#pragma unroll
    for (int rg = 0; rg < 4; ++rg) ssr[rg] += accO[nt][rg] * accO[nt][rg];
#pragma unroll
  for (int m = 1; m <= 8; m <<= 1)
#pragma unroll
    for (int rg = 0; rg < 4; ++rg) ssr[rg] += __shfl_xor(ssr[rg], m);
  float rinv[4];
#pragma unroll
  for (int rg = 0; rg < 4; ++rg) rinv[rg] = 0.2f / sqrtf(ssr[rg] * (1.f / 128.f) + 1e-6f);
#pragma unroll
  for (int nt = 0; nt < 8; ++nt) {
    float wcol = hw[nt * 16 + lr];
#pragma unroll
    for (int rg = 0; rg < 4; ++rg) {
      int i = qt * 16 + quad * 4 + rg;
      anorm[(size_t)(b * RR + i) * 1024 + h * 128 + nt * 16 + lr] = (bf16_t)(accO[nt][rg] * rinv[rg] * wcol);
    }
  }
}

// ---------------- K6: upsample lowrank (B,512,1024) f32 -> full (B,4096,1024) f32 --------
__global__ void k_up(const float* __restrict__ lrk, float* __restrict__ out) {
  int j = blockIdx.x;
  int b = blockIdx.y;
  int c = threadIdx.x * 4;
  float coord = 0.125f * (float)j - 0.4375f;
  coord = fminf(fmaxf(coord, 0.f), 511.f);
  int lo = (int)floorf(coord);
  int hi = lo + 1 < 511 ? lo + 1 : 511;
  float w = coord - (float)lo;
  f32x4 a = *(const f32x4*)&lrk[(size_t)(b * RR + lo) * CC + c];
  f32x4 bb = *(const f32x4*)&lrk[(size_t)(b * RR + hi) * CC + c];
  f32x4 o;
#pragma unroll
  for (int t = 0; t < 4; ++t) o[t] = a[t] * (1.f - w) + bb[t] * w;
  *(f32x4*)&out[(size_t)(b * LL + j) * CC + c] = o;
}

extern "C" void kernel_launch(void* const* d_in, const int* in_sizes, int n_in,
                              void* d_out, int out_size, void* d_ws, size_t ws_size,
                              hipStream_t stream) {
  (void)in_sizes; (void)n_in; (void)out_size; (void)ws_size;
  const float* x   = (const float*)d_in[0];
  const float* Wq  = (const float*)d_in[1];
  const float* Wk  = (const float*)d_in[2];
  const float* Wv  = (const float*)d_in[3];
  const float* Wo  = (const float*)d_in[4];
  const float* qw  = (const float*)d_in[5];
  const float* kw  = (const float*)d_in[6];
  const float* hw  = (const float*)d_in[7];
  const float* lq1 = (const float*)d_in[8];
  const float* lk1 = (const float*)d_in[9];
  const float* lq2 = (const float*)d_in[10];
  const float* lk2 = (const float*)d_in[11];
  float* out = (float*)d_out;

  char* ws = (char*)d_ws;
  bf16_t* wbf   = (bf16_t*)(ws);                    // 8 MB: Wq,Wk,Wv,Wo bf16
  bf16_t* xd    = (bf16_t*)(ws + (8u << 20));       // 4 MB
  bf16_t* vt    = (bf16_t*)(ws + (12u << 20));      // 4 MB (B,H,128,512)
  bf16_t* q1    = (bf16_t*)(ws + (16u << 20));      // 2 MB each
  bf16_t* q2    = (bf16_t*)(ws + (18u << 20));
  bf16_t* k1    = (bf16_t*)(ws + (20u << 20));
  bf16_t* k2    = (bf16_t*)(ws + (22u << 20));
  bf16_t* anorm = (bf16_t*)(ws + (24u << 20));      // 4 MB -> 28 MB total

  float* lowrank = out + (size_t)NB * LL * CC;      // second output region (f32)

  k_wcvt<<<dim3(1024, 4), 256, 0, stream>>>(Wq, Wk, Wv, Wo, wbf);
  k_down<<<2048, 256, 0, stream>>>(x, xd);
  k_gemm<0, 128><<<dim3(8, 16, 3), 256, 0, stream>>>(xd, wbf, qw, kw, q1, q2, k1, k2, vt, nullptr);
  k_attn<<<dim3(32, 32), 64, 0, stream>>>(q1, q2, k1, k2, vt, lq1, lk1, lq2, lk2, hw, anorm);
  k_gemm<1, 64><<<dim3(8, 32, 1), 256, 0, stream>>>(anorm, wbf, qw, kw, nullptr, nullptr, nullptr, nullptr, nullptr, lowrank);
  k_up<<<dim3(4096, 4), 256, 0, stream>>>(lowrank, out);
}

// Round 4
// 237.949 us; speedup vs baseline: 1.4308x; 1.2110x over previous
//
#include <hip/hip_runtime.h>

typedef __bf16 bf16_t;
typedef __bf16 bf16x8 __attribute__((ext_vector_type(8)));
typedef __bf16 bf16x4 __attribute__((ext_vector_type(4)));
typedef float  f32x4  __attribute__((ext_vector_type(4)));

#define MFMA16(a,b,c) __builtin_amdgcn_mfma_f32_16x16x32_bf16((a),(b),(c),0,0,0)

#define NB 4          // batch
#define LL 4096       // seq
#define CC 1024       // channels
#define HH 8          // heads
#define RR 512        // low-rank seq

// ---------------- K0: convert 4 weight matrices (1024x1024 f32) -> bf16 ----------------
__global__ void k_wcvt(const float* __restrict__ w0, const float* __restrict__ w1,
                       const float* __restrict__ w2, const float* __restrict__ w3,
                       bf16_t* __restrict__ dst) {
  const float* src = (blockIdx.y == 0) ? w0 : (blockIdx.y == 1) ? w1 : (blockIdx.y == 2) ? w2 : w3;
  int idx = blockIdx.x * 256 + threadIdx.x;       // one thread = 4 elems
  f32x4 v = *(const f32x4*)&src[(size_t)idx * 4];
  bf16x4 o;
#pragma unroll
  for (int j = 0; j < 4; ++j) o[j] = (bf16_t)v[j];
  *(bf16x4*)&dst[(size_t)blockIdx.y * 1048576 + (size_t)idx * 4] = o;
}

// ---------------- K1: downsample x (B,4096,1024) f32 -> xd (B,512,1024) bf16 ----------------
// coords = 8i+3.5 exactly -> xd[i] = 0.5*(x[8i+3]+x[8i+4])
__global__ void k_down(const float* __restrict__ x, bf16_t* __restrict__ xd) {
  int idx = blockIdx.x * 256 + threadIdx.x;       // one thread = 4 elems
  int c4  = idx & 255;
  int row = idx >> 8;                              // b*512 + i
  int b = row >> 9, i = row & 511;
  const float* p0 = x + (size_t)(b * LL + 8 * i + 3) * CC + c4 * 4;
  f32x4 a = *(const f32x4*)p0;
  f32x4 bb = *(const f32x4*)(p0 + CC);
  bf16x4 o;
#pragma unroll
  for (int j = 0; j < 4; ++j) o[j] = (bf16_t)(0.5f * (a[j] + bb[j]));
  *(bf16x4*)&xd[(size_t)row * CC + c4 * 4] = o;
}

// ---------------- async 16B global->LDS staging (m97 pattern: unpadded stride-32 rows) ----
template <int CH>
__device__ __forceinline__ void stage_async(const bf16_t* __restrict__ g, bf16_t* __restrict__ s, int t) {
#pragma unroll
  for (int j = 0; j < CH; ++j) {
    int c = t + j * 256;                     // 16B chunk id; lane-contiguous per wave
    const bf16_t* ga = g + (c >> 2) * 1024 + (c & 3) * 8;
    bf16_t* la = s + c * 8;
    __builtin_amdgcn_global_load_lds((const __attribute__((address_space(1))) void*)ga,
                                     (__attribute__((address_space(3))) void*)la, 16, 0, 0);
  }
}

// ---------------- GEMM core: C[M,N] = A[M,1024] * W[N,1024]^T ----------------
// MODE 0 (BM=128): QKV fused. z=0 -> rmsnorm+rope -> q1/q2 (scaled 0.125)
//                              z=1 -> rmsnorm+rope -> k1/k2
//                              z=2 -> Vt transposed bf16 (B,H,128,512)
// MODE 1 (BM=64):  Wo + silu -> f32 lowrank
template <int MODE, int BM>
__global__ __launch_bounds__(256) void k_gemm(const bf16_t* __restrict__ A,
                                              const bf16_t* __restrict__ wbf,
                                              const float* __restrict__ qw,
                                              const float* __restrict__ kw,
                                              bf16_t* __restrict__ q1, bf16_t* __restrict__ q2,
                                              bf16_t* __restrict__ k1, bf16_t* __restrict__ k2,
                                              bf16_t* __restrict__ vt, float* __restrict__ outF) {
  __shared__ bf16_t sA[BM * 32];
  __shared__ bf16_t sB[128 * 32];
  const int z = (MODE == 0) ? blockIdx.z : 3;
  const bf16_t* W = wbf + (size_t)z * (1u << 20);
  int t = threadIdx.x;
  int lane = t & 63, w = t >> 6;
  int wr = w >> 1, wc = w & 1;
  int lr = lane & 15, quad = lane >> 4;
  int m0 = blockIdx.y * BM, n0 = blockIdx.x * 128;
  const int NI = BM / 32;                     // 16-row tiles per wave
  f32x4 acc[NI][4] = {};
  for (int k0 = 0; k0 < 1024; k0 += 32) {
    __syncthreads();
    stage_async<BM / 64>(A + (size_t)m0 * 1024 + k0, sA, t);
    stage_async<2>(W + (size_t)n0 * 1024 + k0, sB, t);
    __syncthreads();                          // compiler emits vmcnt(0) drain here
    bf16x8 af[NI], bfr[4];
#pragma unroll
    for (int i = 0; i < NI; ++i) af[i] = *(bf16x8*)&sA[(wr * (BM / 2) + i * 16 + lr) * 32 + quad * 8];
#pragma unroll
    for (int j = 0; j < 4; ++j) bfr[j] = *(bf16x8*)&sB[(wc * 64 + j * 16 + lr) * 32 + quad * 8];
#pragma unroll
    for (int i = 0; i < NI; ++i)
#pragma unroll
      for (int j = 0; j < 4; ++j)
        acc[i][j] = MFMA16(af[i], bfr[j], acc[i][j]);
  }

  if (MODE == 1) {
    // silu -> f32
#pragma unroll
    for (int i = 0; i < NI; ++i)
#pragma unroll
      for (int j = 0; j < 4; ++j) {
        int row0 = m0 + wr * (BM / 2) + i * 16 + quad * 4;
        int col  = n0 + wc * 64 + j * 16 + lr;
#pragma unroll
        for (int rg = 0; rg < 4; ++rg) {
          float v = acc[i][j][rg];
          outF[(size_t)(row0 + rg) * 1024 + col] = v / (1.f + __expf(-v));
        }
      }
    return;
  }

  if (z == 2) {
    // Vt transposed bf16 out
#pragma unroll
    for (int i = 0; i < NI; ++i)
#pragma unroll
      for (int j = 0; j < 4; ++j) {
        int row0 = m0 + wr * (BM / 2) + i * 16 + quad * 4;
        int col  = n0 + wc * 64 + j * 16 + lr;
        int b = row0 >> 9, ii = row0 & 511;
        int h = col >> 7, nn = col & 127;
        bf16x4 pk;
#pragma unroll
        for (int rg = 0; rg < 4; ++rg) pk[rg] = (bf16_t)acc[i][j][rg];
        *(bf16x4*)&vt[(size_t)((b * HH + h) * 128 + nn) * 512 + ii] = pk;
      }
    return;
  }

  // z<2: fused rmsnorm(64) + rope (pos = head idx) epilogue.
  // wave col span = n0+wc*64 .. +63 = exactly one (h,slot,d0..63) group.
  {
    const float* nw = z ? kw : qw;
    int colbase = n0 + wc * 64;
    int h = colbase >> 7;
    int slot = (colbase >> 6) & 1;
    bf16_t* dst = (z == 0) ? (slot ? q2 : q1) : (slot ? k2 : k1);
    float qs = (z == 0) ? 0.125f : 1.0f;      // fold attn scale into q
    float w0 = nw[lr], w1 = nw[16 + lr], w2 = nw[32 + lr], w3 = nw[48 + lr];
    const float nlog = -13.287712379549449f / 32.f;   // -log2(10000)/32
    float f0 = exp2f((float)lr * nlog);
    float f1 = exp2f((float)(16 + lr) * nlog);
    float sn0, cs0, sn1, cs1;
    __sincosf((float)h * f0, &sn0, &cs0);
    __sincosf((float)h * f1, &sn1, &cs1);
#pragma unroll
    for (int i = 0; i < NI; ++i) {
#pragma unroll
      for (int rg = 0; rg < 4; ++rg) {
        float v0 = acc[i][0][rg], v1 = acc[i][1][rg], v2 = acc[i][2][rg], v3 = acc[i][3][rg];
        float ss = v0 * v0 + v1 * v1 + v2 * v2 + v3 * v3;
#pragma unroll
        for (int m = 1; m <= 8; m <<= 1) ss += __shfl_xor(ss, m);   // over 16 lr lanes (same row)
        float rinv = qs / sqrtf(ss * (1.f / 64.f) + 1e-6f);
        float n0v = v0 * rinv * w0, n1v = v1 * rinv * w1, n2v = v2 * rinv * w2, n3v = v3 * rinv * w3;
        float o0 = n0v * cs0 - n2v * sn0;
        float o1 = n1v * cs1 - n3v * sn1;
        float o2 = n0v * sn0 + n2v * cs0;
        float o3 = n1v * sn1 + n3v * cs1;
        int row = m0 + wr * (BM / 2) + i * 16 + quad * 4 + rg;
        int b = row >> 9, seq = row & 511;
        size_t base = ((size_t)((b * HH + h) * RR + seq)) * 64;
        dst[base + lr]      = (bf16_t)o0;
        dst[base + 16 + lr] = (bf16_t)o1;
        dst[base + 32 + lr] = (bf16_t)o2;
        dst[base + 48 + lr] = (bf16_t)o3;
      }
    }
  }
}

// ---------------- K4: fused differential attention, 4 waves / block ----------------
// Block handles 16 q rows of one (b,h). Wave w owns K-slice [w*128, w*128+128)
// for scores (no spills: 8 f32x4 per stream) and output cols [w*32, w*32+32) for PV.
// Cross-wave softmax via log-sum-exp merge of per-wave (m,l) stats in LDS.
__global__ __launch_bounds__(256) void k_attn(const bf16_t* __restrict__ q1, const bf16_t* __restrict__ q2,
                                              const bf16_t* __restrict__ k1, const bf16_t* __restrict__ k2,
                                              const bf16_t* __restrict__ vt,
                                              const float* __restrict__ lq1, const float* __restrict__ lk1,
                                              const float* __restrict__ lq2, const float* __restrict__ lk2,
                                              const float* __restrict__ hw, bf16_t* __restrict__ anorm) {
  __shared__ bf16_t P[16 * 520];     // combined P1 - lam*P2 (A-layout source for PV)
  __shared__ float Sm1[4][16], Sl1[4][16], Sm2[4][16], Sl2[4][16], Sq[4][16];
  int t = threadIdx.x;
  int lane = t & 63, w = t >> 6;
  int lr = lane & 15, quad = lane >> 4;
  int qt = blockIdx.x, bh = blockIdx.y;
  int b = bh >> 3, h = bh & 7;

  // lambda scalar
  float t1 = lq1[lane] * lk1[lane];
  float t2 = lq2[lane] * lk2[lane];
#pragma unroll
  for (int m = 1; m <= 32; m <<= 1) { t1 += __shfl_xor(t1, m); t2 += __shfl_xor(t2, m); }
  float lam = expf(t1) - expf(t2) + 0.8f;

  const bf16_t* q1b = q1 + (size_t)(bh * RR + qt * 16) * 64;
  const bf16_t* q2b = q2 + (size_t)(bh * RR + qt * 16) * 64;
  const bf16_t* k1b = k1 + (size_t)bh * RR * 64;
  const bf16_t* k2b = k2 + (size_t)bh * RR * 64;
  const bf16_t* vtb = vt + (size_t)bh * 128 * 512;

  bf16x8 a1[2], a2[2];
#pragma unroll
  for (int kk = 0; kk < 2; ++kk) {
    a1[kk] = *(const bf16x8*)&q1b[lr * 64 + kk * 32 + quad * 8];
    a2[kk] = *(const bf16x8*)&q2b[lr * 64 + kk * 32 + quad * 8];
  }

  // ---- scores for this wave's K-slice (8 kt tiles per stream) ----
  f32x4 s1[8], s2[8];
#pragma unroll
  for (int kt = 0; kt < 8; ++kt) {
    const bf16_t* kr = k1b + (size_t)((w * 8 + kt) * 16 + lr) * 64 + quad * 8;
    f32x4 a = {};
    a = MFMA16(a1[0], *(const bf16x8*)kr, a);
    a = MFMA16(a1[1], *(const bf16x8*)(kr + 32), a);
    s1[kt] = a;
  }
#pragma unroll
  for (int kt = 0; kt < 8; ++kt) {
    const bf16_t* kr = k2b + (size_t)((w * 8 + kt) * 16 + lr) * 64 + quad * 8;
    f32x4 a = {};
    a = MFMA16(a2[0], *(const bf16x8*)kr, a);
    a = MFMA16(a2[1], *(const bf16x8*)(kr + 32), a);
    s2[kt] = a;
  }
  // ---- per-wave softmax stats (rows live across 16 lr lanes) ----
  float m1[4] = {-3e38f, -3e38f, -3e38f, -3e38f}, m2[4] = {-3e38f, -3e38f, -3e38f, -3e38f};
#pragma unroll
  for (int kt = 0; kt < 8; ++kt)
#pragma unroll
    for (int rg = 0; rg < 4; ++rg) { m1[rg] = fmaxf(m1[rg], s1[kt][rg]); m2[rg] = fmaxf(m2[rg], s2[kt][rg]); }
#pragma unroll
  for (int m = 1; m <= 8; m <<= 1)
#pragma unroll
    for (int rg = 0; rg < 4; ++rg) { m1[rg] = fmaxf(m1[rg], __shfl_xor(m1[rg], m)); m2[rg] = fmaxf(m2[rg], __shfl_xor(m2[rg], m)); }
  float l1[4] = {}, l2[4] = {};
#pragma unroll
  for (int kt = 0; kt < 8; ++kt)
#pragma unroll
    for (int rg = 0; rg < 4; ++rg) {
      float e1 = __expf(s1[kt][rg] - m1[rg]); s1[kt][rg] = e1; l1[rg] += e1;
      float e2 = __expf(s2[kt][rg] - m2[rg]); s2[kt][rg] = e2; l2[rg] += e2;
    }
#pragma unroll
  for (int m = 1; m <= 8; m <<= 1)
#pragma unroll
    for (int rg = 0; rg < 4; ++rg) { l1[rg] += __shfl_xor(l1[rg], m); l2[rg] += __shfl_xor(l2[rg], m); }
  if (lr == 0) {
#pragma unroll
    for (int rg = 0; rg < 4; ++rg) {
      int r = quad * 4 + rg;
      Sm1[w][r] = m1[rg]; Sl1[w][r] = l1[rg];
      Sm2[w][r] = m2[rg]; Sl2[w][r] = l2[rg];
    }
  }
  __syncthreads();
  // ---- merge stats across waves, write combined P slice ----
  float sc1[4], sc2[4];
#pragma unroll
  for (int rg = 0; rg < 4; ++rg) {
    int r = quad * 4 + rg;
    float gm1 = fmaxf(fmaxf(Sm1[0][r], Sm1[1][r]), fmaxf(Sm1[2][r], Sm1[3][r]));
    float L1 = Sl1[0][r] * __expf(Sm1[0][r] - gm1) + Sl1[1][r] * __expf(Sm1[1][r] - gm1)
             + Sl1[2][r] * __expf(Sm1[2][r] - gm1) + Sl1[3][r] * __expf(Sm1[3][r] - gm1);
    sc1[rg] = __expf(m1[rg] - gm1) / L1;
    float gm2 = fmaxf(fmaxf(Sm2[0][r], Sm2[1][r]), fmaxf(Sm2[2][r], Sm2[3][r]));
    float L2 = Sl2[0][r] * __expf(Sm2[0][r] - gm2) + Sl2[1][r] * __expf(Sm2[1][r] - gm2)
             + Sl2[2][r] * __expf(Sm2[2][r] - gm2) + Sl2[3][r] * __expf(Sm2[3][r] - gm2);
    sc2[rg] = lam * __expf(m2[rg] - gm2) / L2;
  }
#pragma unroll
  for (int kt = 0; kt < 8; ++kt)
#pragma unroll
    for (int rg = 0; rg < 4; ++rg) {
      float v = s1[kt][rg] * sc1[rg] - s2[kt][rg] * sc2[rg];
      P[(quad * 4 + rg) * 520 + (w * 8 + kt) * 16 + lr] = (bf16_t)v;
    }
  __syncthreads();
  // ---- PV: this wave computes output cols [w*32, w*32+32) ----
  f32x4 accO[2] = {};
#pragma unroll
  for (int ks = 0; ks < 16; ++ks) {
    bf16x8 pf = *(bf16x8*)&P[lr * 520 + ks * 32 + quad * 8];
#pragma unroll
    for (int j = 0; j < 2; ++j) {
      int nt = w * 2 + j;
      bf16x8 vf = *(const bf16x8*)&vtb[(size_t)(nt * 16 + lr) * 512 + ks * 32 + quad * 8];
      accO[j] = MFMA16(pf, vf, accO[j]);
    }
  }
  // ---- head rmsnorm(128): partial squares per wave, LDS combine ----
  float ssr[4] = {};
#pragma unroll
  for (int j = 0; j < 2; ++j)
#pragma unroll
    for (int rg = 0; rg < 4; ++rg) ssr[rg] += accO[j][rg] * accO[j][rg];
#pragma unroll
  for (int m = 1; m <= 8; m <<= 1)
#pragma unroll
    for (int rg = 0; rg < 4; ++rg) ssr[rg] += __shfl_xor(ssr[rg], m);
  if (lr == 0) {
#pragma unroll
    for (int rg = 0; rg < 4; ++rg) Sq[w][quad * 4 + rg] = ssr[rg];
  }
  __syncthreads();
#pragma unroll
  for (int j = 0; j < 2; ++j) {
    int nt = w * 2 + j;
    float wcol = hw[nt * 16 + lr];
#pragma unroll
    for (int rg = 0; rg < 4; ++rg) {
      int r = quad * 4 + rg;
      float tot = Sq[0][r] + Sq[1][r] + Sq[2][r] + Sq[3][r];
      float rinv = 0.2f / sqrtf(tot * (1.f / 128.f) + 1e-6f);
      int i = qt * 16 + r;
      anorm[(size_t)(b * RR + i) * 1024 + h * 128 + nt * 16 + lr] = (bf16_t)(accO[j][rg] * rinv * wcol);
    }
  }
}

// ---------------- K6: upsample lowrank (B,512,1024) f32 -> full (B,4096,1024) f32 --------
__global__ void k_up(const float* __restrict__ lrk, float* __restrict__ out) {
  int j = blockIdx.x;
  int b = blockIdx.y;
  int c = threadIdx.x * 4;
  float coord = 0.125f * (float)j - 0.4375f;
  coord = fminf(fmaxf(coord, 0.f), 511.f);
  int lo = (int)floorf(coord);
  int hi = lo + 1 < 511 ? lo + 1 : 511;
  float w = coord - (float)lo;
  f32x4 a = *(const f32x4*)&lrk[(size_t)(b * RR + lo) * CC + c];
  f32x4 bb = *(const f32x4*)&lrk[(size_t)(b * RR + hi) * CC + c];
  f32x4 o;
#pragma unroll
  for (int t = 0; t < 4; ++t) o[t] = a[t] * (1.f - w) + bb[t] * w;
  *(f32x4*)&out[(size_t)(b * LL + j) * CC + c] = o;
}

extern "C" void kernel_launch(void* const* d_in, const int* in_sizes, int n_in,
                              void* d_out, int out_size, void* d_ws, size_t ws_size,
                              hipStream_t stream) {
  (void)in_sizes; (void)n_in; (void)out_size; (void)ws_size;
  const float* x   = (const float*)d_in[0];
  const float* Wq  = (const float*)d_in[1];
  const float* Wk  = (const float*)d_in[2];
  const float* Wv  = (const float*)d_in[3];
  const float* Wo  = (const float*)d_in[4];
  const float* qw  = (const float*)d_in[5];
  const float* kw  = (const float*)d_in[6];
  const float* hw  = (const float*)d_in[7];
  const float* lq1 = (const float*)d_in[8];
  const float* lk1 = (const float*)d_in[9];
  const float* lq2 = (const float*)d_in[10];
  const float* lk2 = (const float*)d_in[11];
  float* out = (float*)d_out;

  char* ws = (char*)d_ws;
  bf16_t* wbf   = (bf16_t*)(ws);                    // 8 MB: Wq,Wk,Wv,Wo bf16
  bf16_t* xd    = (bf16_t*)(ws + (8u << 20));       // 4 MB
  bf16_t* vt    = (bf16_t*)(ws + (12u << 20));      // 4 MB (B,H,128,512)
  bf16_t* q1    = (bf16_t*)(ws + (16u << 20));      // 2 MB each
  bf16_t* q2    = (bf16_t*)(ws + (18u << 20));
  bf16_t* k1    = (bf16_t*)(ws + (20u << 20));
  bf16_t* k2    = (bf16_t*)(ws + (22u << 20));
  bf16_t* anorm = (bf16_t*)(ws + (24u << 20));      // 4 MB -> 28 MB total

  float* lowrank = out + (size_t)NB * LL * CC;      // second output region (f32)

  k_wcvt<<<dim3(1024, 4), 256, 0, stream>>>(Wq, Wk, Wv, Wo, wbf);
  k_down<<<2048, 256, 0, stream>>>(x, xd);
  k_gemm<0, 128><<<dim3(8, 16, 3), 256, 0, stream>>>(xd, wbf, qw, kw, q1, q2, k1, k2, vt, nullptr);
  k_attn<<<dim3(32, 32), 256, 0, stream>>>(q1, q2, k1, k2, vt, lq1, lk1, lq2, lk2, hw, anorm);
  k_gemm<1, 64><<<dim3(8, 32, 1), 256, 0, stream>>>(anorm, wbf, qw, kw, nullptr, nullptr, nullptr, nullptr, nullptr, lowrank);
  k_up<<<dim3(4096, 4), 256, 0, stream>>>(lowrank, out);
}